// Round 1
// baseline (197.031 us; speedup 1.0000x reference)
//
#include <hip/hip_runtime.h>

#define B_ 8
#define C_ 4
#define H_ 256
#define W_ 256
#define NIMG (B_ * C_)
#define HW (H_ * W_)
#define INF_ 1.0e6f

// Stage 1: per-column distance-to-nearest-zero along H (down + up scans),
// squared, written to buf[n][h][w]. One thread per (image, column).
__global__ void coldist_kernel(const int* __restrict__ y, float* __restrict__ buf) {
    const int n = blockIdx.x;            // image index: b*C + c
    const int b = n >> 2;
    const int c = n & 3;
    const int w = blockIdx.y * blockDim.x + threadIdx.x;  // column
    const int* __restrict__ yb = y + b * HW;
    float* __restrict__ g = buf + n * HW;

    float d = INF_;
#pragma unroll 8
    for (int h = 0; h < H_; ++h) {
        const int f = (yb[h * W_ + w] == c);
        d = f ? fminf(d + 1.0f, INF_) : 0.0f;
        g[h * W_ + w] = d;
    }
    d = INF_;
#pragma unroll 8
    for (int h = H_ - 1; h >= 0; --h) {
        const int f = (yb[h * W_ + w] == c);
        d = f ? fminf(d + 1.0f, INF_) : 0.0f;
        const float m = fminf(d, g[h * W_ + w]);
        g[h * W_ + w] = m * m;  // store squared column distance
    }
}

// Stage 2: exact 1D min-plus along W per row: D2[x] = min_j(g2[j] + (x-j)^2),
// then sqrt -> d. In-place over buf row. Also per-image max via atomicMax.
__global__ void minplus_kernel(float* __restrict__ buf, float* __restrict__ mx) {
    const int row = blockIdx.x;   // n*H + h
    const int n = row >> 8;
    float* __restrict__ g = buf + row * W_;
    __shared__ float s[W_];
    const int x = threadIdx.x;
    s[x] = g[x];
    __syncthreads();

    float m = 3.0e12f;  // > 1e12 + 255^2
    const float fx = (float)x;
#pragma unroll 8
    for (int j = 0; j < W_; ++j) {
        const float df = fx - (float)j;
        m = fminf(m, fmaf(df, df, s[j]));
    }
    const float d = sqrtf(m);
    g[x] = d;

    // block max reduction
    float v = d;
#pragma unroll
    for (int off = 32; off > 0; off >>= 1) v = fmaxf(v, __shfl_down(v, off));
    __shared__ float smax[4];
    if ((x & 63) == 0) smax[x >> 6] = v;
    __syncthreads();
    if (x == 0) {
        const float bm = fmaxf(fmaxf(smax[0], smax[1]), fmaxf(smax[2], smax[3]));
        atomicMax((int*)(mx + n), __float_as_int(bm));  // valid: all d >= 0
    }
}

// Stage 3: softmax over C + rrwmap + partial sums (one thread per pixel).
__global__ void final_kernel(const float* __restrict__ x, const float* __restrict__ buf,
                             const float* __restrict__ mx, float* __restrict__ partial) {
    const int idx = blockIdx.x * blockDim.x + threadIdx.x;  // < B*H*W
    const int b = idx >> 16;        // HW = 65536
    const int hw = idx & (HW - 1);

    const float* __restrict__ xb = x + b * (C_ * HW) + hw;
    float xv[C_];
    float xm = -3.0e38f;
#pragma unroll
    for (int c = 0; c < C_; ++c) { xv[c] = xb[c * HW]; xm = fmaxf(xm, xv[c]); }
    float e[C_];
    float se = 0.0f;
#pragma unroll
    for (int c = 0; c < C_; ++c) { e[c] = expf(xv[c] - xm); se += e[c]; }
    const float inv = 1.0f / se;

    const float* __restrict__ db = buf + b * (C_ * HW) + hw;
    float acc = 0.0f;
#pragma unroll
    for (int c = 0; c < C_; ++c) {
        const float d = db[c * HW];
        float r = -d / (mx[b * C_ + c] + 1e-15f);
        if (r == 0.0f) r = 1.0f;   // background pixels: -0.0 -> 1.0
        acc = fmaf(e[c] * inv, r, acc);
    }

    // block sum reduction -> one partial per block (deterministic)
#pragma unroll
    for (int off = 32; off > 0; off >>= 1) acc += __shfl_down(acc, off);
    __shared__ float ss[4];
    if ((threadIdx.x & 63) == 0) ss[threadIdx.x >> 6] = acc;
    __syncthreads();
    if (threadIdx.x == 0) partial[blockIdx.x] = ss[0] + ss[1] + ss[2] + ss[3];
}

// Stage 4: sum the 2048 block partials, scale by 1/(B*C*H*W).
__global__ void reduce_kernel(const float* __restrict__ partial, int np,
                              float* __restrict__ out) {
    float acc = 0.0f;
    for (int i = threadIdx.x; i < np; i += blockDim.x) acc += partial[i];
#pragma unroll
    for (int off = 32; off > 0; off >>= 1) acc += __shfl_down(acc, off);
    __shared__ float ss[4];
    if ((threadIdx.x & 63) == 0) ss[threadIdx.x >> 6] = acc;
    __syncthreads();
    if (threadIdx.x == 0)
        out[0] = (ss[0] + ss[1] + ss[2] + ss[3]) * (1.0f / (float)(NIMG * HW));
}

extern "C" void kernel_launch(void* const* d_in, const int* in_sizes, int n_in,
                              void* d_out, int out_size, void* d_ws, size_t ws_size,
                              hipStream_t stream) {
    const float* x = (const float*)d_in[0];   // [B, C, H, W] f32
    const int* y = (const int*)d_in[1];       // [B, 1, H, W] i32
    float* out = (float*)d_out;               // scalar f32

    float* buf = (float*)d_ws;                // [NIMG, H, W] dist buffer (8 MB)
    float* mx = buf + (size_t)NIMG * HW;      // [NIMG] per-image max
    float* partial = mx + NIMG;               // [2048] block partials

    hipMemsetAsync(mx, 0, NIMG * sizeof(float), stream);

    dim3 g1(NIMG, 4);
    coldist_kernel<<<g1, 64, 0, stream>>>(y, buf);

    minplus_kernel<<<NIMG * H_, 256, 0, stream>>>(buf, mx);

    const int nblocks = (B_ * HW) / 256;      // 2048
    final_kernel<<<nblocks, 256, 0, stream>>>(x, buf, mx, partial);

    reduce_kernel<<<1, 256, 0, stream>>>(partial, nblocks, out);
}

// Round 2
// 116.455 us; speedup vs baseline: 1.6919x; 1.6919x over previous
//
#include <hip/hip_runtime.h>

#define B_ 8
#define C_ 4
#define H_ 256
#define W_ 256
#define NIMG (B_ * C_)
#define HW (H_ * W_)
#define INF_ 1.0e6f
#define PADV 2.0e12f  // pad candidate: PADV + k^2 > 1e12 >= any true D2

// Stage 1: per-column distance-to-nearest-zero along H (down + up scans),
// squared, written to buf[n][h][w]. One thread per (image, column).
__global__ void coldist_kernel(const int* __restrict__ y, float* __restrict__ buf) {
    const int n = blockIdx.x;            // image index: b*C + c
    const int b = n >> 2;
    const int c = n & 3;
    const int w = blockIdx.y * blockDim.x + threadIdx.x;  // column
    const int* __restrict__ yb = y + b * HW;
    float* __restrict__ g = buf + n * HW;

    float d = INF_;
#pragma unroll 8
    for (int h = 0; h < H_; ++h) {
        const int f = (yb[h * W_ + w] == c);
        d = f ? fminf(d + 1.0f, INF_) : 0.0f;
        g[h * W_ + w] = d;
    }
    d = INF_;
#pragma unroll 8
    for (int h = H_ - 1; h >= 0; --h) {
        const int f = (yb[h * W_ + w] == c);
        d = f ? fminf(d + 1.0f, INF_) : 0.0f;
        const float m = fminf(d, g[h * W_ + w]);
        g[h * W_ + w] = m * m;  // store squared column distance
    }
}

// Stage 2: exact 1D min-plus along W per row, adaptive radius.
// D2[x] = min_j(g2[j] + (x-j)^2). Since j=x gives g2[x], any k with
// k^2 >= m cannot improve -> expand outward, wave-uniform early exit.
__global__ void minplus_kernel(float* __restrict__ buf, float* __restrict__ mx) {
    const int row = blockIdx.x;   // n*H + h
    const int n = row >> 8;
    float* __restrict__ g = buf + row * W_;
    __shared__ float s[W_ + 2 * W_];   // [256 pad | 256 row | 256 pad]
    const int x = threadIdx.x;
    s[x] = PADV;
    s[W_ + x] = g[x];
    s[2 * W_ + x] = PADV;
    __syncthreads();

    float m = s[W_ + x];            // k = 0 candidate: g2[x]
    int alo = W_ + x;
    int ahi = W_ + x;
    float k2 = 0.0f, tk1 = 1.0f;    // k2 = k^2, tk1 = 2k+1 (exact ints in f32)
    for (int k = 1; k < W_; ++k) {
        k2 += tk1;                  // k2 = k*k
        tk1 += 2.0f;
        if (__all(k2 >= m)) break;  // no farther candidate can improve any lane
        --alo; ++ahi;
        const float c1 = s[alo] + k2;
        const float c2 = s[ahi] + k2;
        m = fminf(m, fminf(c1, c2));
    }
    const float d = sqrtf(m);
    g[x] = d;

    // block max reduction
    float v = d;
#pragma unroll
    for (int off = 32; off > 0; off >>= 1) v = fmaxf(v, __shfl_down(v, off));
    __shared__ float smax[4];
    if ((x & 63) == 0) smax[x >> 6] = v;
    __syncthreads();
    if (x == 0) {
        const float bm = fmaxf(fmaxf(smax[0], smax[1]), fmaxf(smax[2], smax[3]));
        atomicMax((int*)(mx + n), __float_as_int(bm));  // valid: all d >= 0
    }
}

// Stage 3: softmax over C + rrwmap + partial sums (one thread per pixel).
__global__ void final_kernel(const float* __restrict__ x, const float* __restrict__ buf,
                             const float* __restrict__ mx, float* __restrict__ partial) {
    const int idx = blockIdx.x * blockDim.x + threadIdx.x;  // < B*H*W
    const int b = idx >> 16;        // HW = 65536
    const int hw = idx & (HW - 1);

    const float* __restrict__ xb = x + b * (C_ * HW) + hw;
    float xv[C_];
    float xm = -3.0e38f;
#pragma unroll
    for (int c = 0; c < C_; ++c) { xv[c] = xb[c * HW]; xm = fmaxf(xm, xv[c]); }
    float e[C_];
    float se = 0.0f;
#pragma unroll
    for (int c = 0; c < C_; ++c) { e[c] = expf(xv[c] - xm); se += e[c]; }
    const float inv = 1.0f / se;

    const float* __restrict__ db = buf + b * (C_ * HW) + hw;
    float acc = 0.0f;
#pragma unroll
    for (int c = 0; c < C_; ++c) {
        const float d = db[c * HW];
        float r = -d / (mx[b * C_ + c] + 1e-15f);
        if (r == 0.0f) r = 1.0f;   // background pixels: -0.0 -> 1.0
        acc = fmaf(e[c] * inv, r, acc);
    }

    // block sum reduction -> one partial per block (deterministic)
#pragma unroll
    for (int off = 32; off > 0; off >>= 1) acc += __shfl_down(acc, off);
    __shared__ float ss[4];
    if ((threadIdx.x & 63) == 0) ss[threadIdx.x >> 6] = acc;
    __syncthreads();
    if (threadIdx.x == 0) partial[blockIdx.x] = ss[0] + ss[1] + ss[2] + ss[3];
}

// Stage 4: sum the 2048 block partials, scale by 1/(B*C*H*W).
__global__ void reduce_kernel(const float* __restrict__ partial, int np,
                              float* __restrict__ out) {
    float acc = 0.0f;
    for (int i = threadIdx.x; i < np; i += blockDim.x) acc += partial[i];
#pragma unroll
    for (int off = 32; off > 0; off >>= 1) acc += __shfl_down(acc, off);
    __shared__ float ss[4];
    if ((threadIdx.x & 63) == 0) ss[threadIdx.x >> 6] = acc;
    __syncthreads();
    if (threadIdx.x == 0)
        out[0] = (ss[0] + ss[1] + ss[2] + ss[3]) * (1.0f / (float)(NIMG * HW));
}

extern "C" void kernel_launch(void* const* d_in, const int* in_sizes, int n_in,
                              void* d_out, int out_size, void* d_ws, size_t ws_size,
                              hipStream_t stream) {
    const float* x = (const float*)d_in[0];   // [B, C, H, W] f32
    const int* y = (const int*)d_in[1];       // [B, 1, H, W] i32
    float* out = (float*)d_out;               // scalar f32

    float* buf = (float*)d_ws;                // [NIMG, H, W] dist buffer (8 MB)
    float* mx = buf + (size_t)NIMG * HW;      // [NIMG] per-image max
    float* partial = mx + NIMG;               // [2048] block partials

    hipMemsetAsync(mx, 0, NIMG * sizeof(float), stream);

    dim3 g1(NIMG, 4);
    coldist_kernel<<<g1, 64, 0, stream>>>(y, buf);

    minplus_kernel<<<NIMG * H_, 256, 0, stream>>>(buf, mx);

    const int nblocks = (B_ * HW) / 256;      // 2048
    final_kernel<<<nblocks, 256, 0, stream>>>(x, buf, mx, partial);

    reduce_kernel<<<1, 256, 0, stream>>>(partial, nblocks, out);
}

// Round 3
// 22.495 us; speedup vs baseline: 8.7588x; 5.1768x over previous
//
#include <hip/hip_runtime.h>

#define B_ 8
#define C_ 4
#define H_ 256
#define W_ 256
#define NIMG (B_ * C_)
#define HW (H_ * W_)
#define INF2 (1.0e6f * 1.0e6f)  // f32 round of 1e12, same as reference g^2
#define PADV 2.0e12f             // pad candidate: PADV + k^2 > any true D2

// One block per (image n = b*C+c, row h). Fuses: column-distance search,
// exact min-plus along W (adaptive radius), softmax weighting, row reduction.
// Emits per-row: A = sum_fg p*d, T = sum_bg p, M = max d.
__global__ void fused_kernel(const int* __restrict__ y, const float* __restrict__ x,
                             float* __restrict__ Arow, float* __restrict__ Trow,
                             float* __restrict__ Mrow) {
    const int row = blockIdx.x;      // n*H + h
    const int n = row >> 8;
    const int h = row & (H_ - 1);
    const int b = n >> 2;
    const int c = n & 3;
    const int tx = threadIdx.x;      // column 0..255
    const int* __restrict__ yb = y + b * HW;

    // ---- inline column distance squared at (h, tx) ----
    float g2;
    {
        const int yv = yb[h * W_ + tx];
        if (yv != c) {
            g2 = 0.0f;               // background: zero pixel
        } else {
            g2 = INF2;               // no zero in column -> capped like reference
            for (int k = 1; k < H_; ++k) {
                const int hu = h - k, hd = h + k;
                bool inb = false, hit = false;
                if (hu >= 0) { inb = true; hit = (yb[hu * W_ + tx] != c); }
                if (hd < H_) { inb = true; hit = hit || (yb[hd * W_ + tx] != c); }
                if (hit) { g2 = (float)(k * k); break; }
                if (!inb) break;
            }
        }
    }

    __shared__ float s[3 * W_];      // [256 pad | 256 g2 | 256 pad]
    s[tx] = PADV;
    s[W_ + tx] = g2;
    s[2 * W_ + tx] = PADV;
    __syncthreads();

    // ---- exact min-plus: D2[x] = min_j (g2[j] + (x-j)^2), adaptive radius ----
    const int base = W_ + tx;
    float m = s[base];               // k = 0
    {   // unrolled k = 1..4: 8 LDS reads issued together, one wait
        const float c1 = fminf(s[base - 1] + 1.0f,  s[base + 1] + 1.0f);
        const float c2 = fminf(s[base - 2] + 4.0f,  s[base + 2] + 4.0f);
        const float c3 = fminf(s[base - 3] + 9.0f,  s[base + 3] + 9.0f);
        const float c4 = fminf(s[base - 4] + 16.0f, s[base + 4] + 16.0f);
        m = fminf(m, fminf(fminf(c1, c2), fminf(c3, c4)));
    }
    if (__any(m > 25.0f)) {          // some lane could still improve at k >= 5
        float k2 = 25.0f, tk1 = 11.0f;   // k2 = k^2, tk1 = 2k+1 (exact ints)
        int alo = base - 5, ahi = base + 5;
        for (int k = 5; k < W_; ++k) {
            const float c1 = s[alo] + k2;
            const float c2 = s[ahi] + k2;
            m = fminf(m, fminf(c1, c2));
            k2 += tk1; tk1 += 2.0f;
            --alo; ++ahi;
            if (__all(k2 >= m)) break;   // next k can't improve any lane
        }
    }
    const float d = sqrtf(m);

    // ---- softmax over channels at this pixel, class-c probability ----
    const float* __restrict__ xb = x + (size_t)b * (C_ * HW) + h * W_ + tx;
    const float x0 = xb[0];
    const float x1 = xb[HW];
    const float x2 = xb[2 * HW];
    const float x3 = xb[3 * HW];
    const float xm = fmaxf(fmaxf(x0, x1), fmaxf(x2, x3));
    const float e0 = expf(x0 - xm), e1 = expf(x1 - xm);
    const float e2 = expf(x2 - xm), e3 = expf(x3 - xm);
    const float inv = 1.0f / (e0 + e1 + e2 + e3);
    const float ec = (c == 0) ? e0 : (c == 1) ? e1 : (c == 2) ? e2 : e3;  // uniform branch
    const float p = ec * inv;

    float a = (m > 0.0f) ? p * d : 0.0f;  // foreground contribution (needs /mx later)
    float t = (m > 0.0f) ? 0.0f : p;      // background contribution (r == 1)
    float mv = d;

    // ---- fixed-order wave butterfly + cross-wave combine ----
#pragma unroll
    for (int off = 1; off < 64; off <<= 1) {
        a += __shfl_xor(a, off);
        t += __shfl_xor(t, off);
        mv = fmaxf(mv, __shfl_xor(mv, off));
    }
    __shared__ float red[12];
    const int wid = tx >> 6;
    if ((tx & 63) == 0) { red[wid] = a; red[4 + wid] = t; red[8 + wid] = mv; }
    __syncthreads();
    if (tx == 0) {
        Arow[row] = red[0] + red[1] + red[2] + red[3];
        Trow[row] = red[4] + red[5] + red[6] + red[7];
        Mrow[row] = fmaxf(fmaxf(red[8], red[9]), fmaxf(red[10], red[11]));
    }
}

// Single block: combine 8192 row partials -> scalar.
// out = (sum T - sum_n A_n / (mx_n + 1e-15)) / (NIMG*HW)
__global__ void finish_kernel(const float* __restrict__ Arow, const float* __restrict__ Trow,
                              const float* __restrict__ Mrow, float* __restrict__ out) {
    const int t = threadIdx.x;       // 256 threads
    const int n = t >> 3;            // 8 threads per image
    const int l = t & 7;
    float a = 0.0f, tt = 0.0f, mm = 0.0f;
#pragma unroll 4
    for (int i = 0; i < 32; ++i) {
        const int r = (n << 8) + l + (i << 3);
        a += Arow[r]; tt += Trow[r]; mm = fmaxf(mm, Mrow[r]);
    }
#pragma unroll
    for (int off = 1; off < 8; off <<= 1) {
        a += __shfl_xor(a, off);
        mm = fmaxf(mm, __shfl_xor(mm, off));
    }
#pragma unroll
    for (int off = 1; off < 64; off <<= 1) tt += __shfl_xor(tt, off);
    __shared__ float sT[4];
    __shared__ float sV[32];
    if ((t & 63) == 0) sT[t >> 6] = tt;
    if (l == 0) sV[n] = a / (mm + 1e-15f);
    __syncthreads();
    if (t == 0) {
        const float T = sT[0] + sT[1] + sT[2] + sT[3];
        float S = 0.0f;
#pragma unroll 8
        for (int i = 0; i < 32; ++i) S += sV[i];
        out[0] = (T - S) * (1.0f / (float)(NIMG * HW));
    }
}

extern "C" void kernel_launch(void* const* d_in, const int* in_sizes, int n_in,
                              void* d_out, int out_size, void* d_ws, size_t ws_size,
                              hipStream_t stream) {
    const float* x = (const float*)d_in[0];   // [B, C, H, W] f32
    const int* y = (const int*)d_in[1];       // [B, 1, H, W] i32
    float* out = (float*)d_out;               // scalar f32

    float* Arow = (float*)d_ws;               // [NIMG*H]
    float* Trow = Arow + NIMG * H_;           // [NIMG*H]
    float* Mrow = Trow + NIMG * H_;           // [NIMG*H]

    fused_kernel<<<NIMG * H_, 256, 0, stream>>>(y, x, Arow, Trow, Mrow);
    finish_kernel<<<1, 256, 0, stream>>>(Arow, Trow, Mrow, out);
}

// Round 4
// 17.689 us; speedup vs baseline: 11.1383x; 1.2717x over previous
//
#include <hip/hip_runtime.h>

#define B_ 8
#define C_ 4
#define H_ 256
#define W_ 256
#define NIMG 32
#define HW 65536
#define NROW 2048                 // B_ * H_
#define INF2 (1.0e6f * 1.0e6f)   // fl(1e12), same value the reference squares to

// One block per (b, h). Only the pixel's OWN class c = y[h][w] has a
// nontrivial EDT; the other 3 channels contribute p_c * 1. Per row emit 9
// partials: A_c = sum_{yv=c} p*d (c=0..3), M_c = max_{yv=c} d, T = sum (1-p_yv).
__global__ void fused_kernel(const int* __restrict__ y, const float* __restrict__ x,
                             float* __restrict__ P) {
    const int row = blockIdx.x;          // b*H + h
    const int b = row >> 8;
    const int h = row & (H_ - 1);
    const int tx = threadIdx.x;          // column
    const int* __restrict__ yb = y + b * HW;

    // independent loads first: 4 softmax channels + own label
    const float* __restrict__ xb = x + (size_t)b * (C_ * HW) + h * W_ + tx;
    const float x0 = xb[0];
    const float x1 = xb[HW];
    const float x2 = xb[2 * HW];
    const float x3 = xb[3 * HW];
    const int yv = yb[h * W_ + tx];

    // ---- column distance^2: nearest row with a different label ----
    float g2 = INF2;
    for (int k = 1; k < H_; ++k) {
        const int hu = h - k, hd = h + k;
        bool hit = false;
        if (hu >= 0) hit = (yb[hu * W_ + tx] != yv);
        if (hd < H_) hit = hit || (yb[hd * W_ + tx] != yv);
        if (hit) { g2 = (float)(k * k); break; }
        if (hu < 0 && hd >= H_) break;
    }

    __shared__ uint2 s2[W_];             // {g2 bits, label}
    s2[tx] = make_uint2(__float_as_uint(g2), (unsigned)yv);
    __syncthreads();

    // ---- exact min-plus along W, adaptive radius, clamped indices ----
    // cand(j,k) = (label[j]==yv ? g2col[j] : 0) + k^2 ; clamped j is dominated
    // by its true-k evaluation, so clamping never changes the min.
    const unsigned cu = (unsigned)yv;
    float m = g2;                        // j = x candidate
#define CAND(J, K2) ({ int j_ = (J); j_ = min(max(j_, 0), W_ - 1);            \
                       const uint2 v_ = s2[j_];                               \
                       (((v_.y == cu) ? __uint_as_float(v_.x) : 0.0f) + (K2)); })
    m = fminf(m, fminf(CAND(tx - 1, 1.0f),  CAND(tx + 1, 1.0f)));
    m = fminf(m, fminf(CAND(tx - 2, 4.0f),  CAND(tx + 2, 4.0f)));
    m = fminf(m, fminf(CAND(tx - 3, 9.0f),  CAND(tx + 3, 9.0f)));
    m = fminf(m, fminf(CAND(tx - 4, 16.0f), CAND(tx + 4, 16.0f)));
    if (__any(m > 25.0f)) {
        float k2 = 25.0f, tk1 = 11.0f;   // k^2, 2k+1 (exact ints in f32)
        for (int k = 5; k < W_; ++k) {
            m = fminf(m, fminf(CAND(tx - k, k2), CAND(tx + k, k2)));
            k2 += tk1; tk1 += 2.0f;
            if (__all(k2 >= m)) break;   // next k can't improve any lane
        }
    }
#undef CAND
    const float d = sqrtf(m);            // own-class distance (>= 1)

    // ---- softmax over channels; contribution split ----
    const float xm = fmaxf(fmaxf(x0, x1), fmaxf(x2, x3));
    const float e0 = expf(x0 - xm), e1 = expf(x1 - xm);
    const float e2 = expf(x2 - xm), e3 = expf(x3 - xm);
    const float se = e0 + e1 + e2 + e3;
    const float inv = 1.0f / se;
    const float ec = (yv == 0) ? e0 : (yv == 1) ? e1 : (yv == 2) ? e2 : e3;
    const float p = ec * inv;            // own-class probability
    float T = (se - ec) * inv;           // other 3 classes: r = 1
    const float a = p * d;               // own class: needs /(mx+eps) later

    float A0 = (yv == 0) ? a : 0.0f, M0 = (yv == 0) ? d : 0.0f;
    float A1 = (yv == 1) ? a : 0.0f, M1 = (yv == 1) ? d : 0.0f;
    float A2 = (yv == 2) ? a : 0.0f, M2 = (yv == 2) ? d : 0.0f;
    float A3 = (yv == 3) ? a : 0.0f, M3 = (yv == 3) ? d : 0.0f;

    // ---- fixed-order wave butterfly + cross-wave combine ----
#pragma unroll
    for (int off = 1; off < 64; off <<= 1) {
        A0 += __shfl_xor(A0, off); A1 += __shfl_xor(A1, off);
        A2 += __shfl_xor(A2, off); A3 += __shfl_xor(A3, off);
        T  += __shfl_xor(T,  off);
        M0 = fmaxf(M0, __shfl_xor(M0, off)); M1 = fmaxf(M1, __shfl_xor(M1, off));
        M2 = fmaxf(M2, __shfl_xor(M2, off)); M3 = fmaxf(M3, __shfl_xor(M3, off));
    }
    __shared__ float red[4][9];
    const int wid = tx >> 6;
    if ((tx & 63) == 0) {
        red[wid][0] = A0; red[wid][1] = A1; red[wid][2] = A2; red[wid][3] = A3;
        red[wid][4] = M0; red[wid][5] = M1; red[wid][6] = M2; red[wid][7] = M3;
        red[wid][8] = T;
    }
    __syncthreads();
    if (tx < 9) {   // slots 0-3: A sums, 4-7: M maxes, 8: T sum
        const float v0 = red[0][tx], v1 = red[1][tx], v2 = red[2][tx], v3 = red[3][tx];
        const float r = (tx >= 4 && tx < 8) ? fmaxf(fmaxf(v0, v1), fmaxf(v2, v3))
                                            : (v0 + v1) + (v2 + v3);
        P[tx * NROW + row] = r;
    }
}

// Single block: P[slot][b*256+h] -> out = (T - sum_{b,c} A/(M+1e-15)) / (B*C*H*W)
__global__ void finish_kernel(const float* __restrict__ P, float* __restrict__ out) {
    const int t = threadIdx.x;           // 256 threads; 32 groups of 8 = (b,c)
    const int g = t >> 3, l = t & 7;
    const int b = g >> 2, c = g & 3;
    const float* Pa = P + c * NROW + b * H_;
    const float* Pm = P + (4 + c) * NROW + b * H_;
    float a = 0.0f, mm = 0.0f;
#pragma unroll 8
    for (int i = 0; i < 32; ++i) {
        a += Pa[l + (i << 3)];
        mm = fmaxf(mm, Pm[l + (i << 3)]);
    }
#pragma unroll
    for (int off = 1; off < 8; off <<= 1) {
        a += __shfl_xor(a, off);
        mm = fmaxf(mm, __shfl_xor(mm, off));
    }
    float tt = 0.0f;
    const float* Pt = P + 8 * NROW;
#pragma unroll
    for (int i = 0; i < 8; ++i) tt += Pt[t + (i << 8)];
#pragma unroll
    for (int off = 1; off < 64; off <<= 1) tt += __shfl_xor(tt, off);
    __shared__ float sV[32];
    __shared__ float sT[4];
    if (l == 0) sV[g] = a / (mm + 1e-15f);
    if ((t & 63) == 0) sT[t >> 6] = tt;
    __syncthreads();
    if (t == 0) {
        float S = 0.0f;
#pragma unroll
        for (int i = 0; i < 32; ++i) S += sV[i];
        const float T = (sT[0] + sT[1]) + (sT[2] + sT[3]);
        out[0] = (T - S) * (1.0f / 2097152.0f);   // / (B*C*H*W)
    }
}

extern "C" void kernel_launch(void* const* d_in, const int* in_sizes, int n_in,
                              void* d_out, int out_size, void* d_ws, size_t ws_size,
                              hipStream_t stream) {
    const float* x = (const float*)d_in[0];   // [B, C, H, W] f32
    const int* y = (const int*)d_in[1];       // [B, 1, H, W] i32
    float* out = (float*)d_out;               // scalar f32
    float* P = (float*)d_ws;                  // [9][NROW] partials (72 KB)

    fused_kernel<<<NROW, 256, 0, stream>>>(y, x, P);
    finish_kernel<<<1, 256, 0, stream>>>(P, out);
}

// Round 5
// 17.176 us; speedup vs baseline: 11.4710x; 1.0299x over previous
//
#include <hip/hip_runtime.h>

#define B_ 8
#define C_ 4
#define H_ 256
#define W_ 256
#define NIMG 32
#define HW 65536
#define NROW 2048                 // B_ * H_
#define INF2 (1.0e6f * 1.0e6f)   // fl(1e12), same as reference capped scan squared

// One block per (b, h). Only the pixel's OWN class c = y[h][w] has a
// nontrivial EDT; the other 3 channels contribute p_c * 1. Per row emit 9
// partials: A_c = sum_{yv=c} p*d, M_c = max_{yv=c} d (c=0..3), T = sum (1-p_yv).
__global__ __launch_bounds__(256) void fused_kernel(const int* __restrict__ y,
                                                    const float* __restrict__ x,
                                                    float* __restrict__ P) {
    const int row = blockIdx.x;          // b*H + h
    const int b = row >> 8;
    const int h = row & (H_ - 1);
    const int tx = threadIdx.x;          // column
    const int* __restrict__ yb = y + b * HW;

    // ---- issue ALL independent loads upfront: 4 x-channels, own label,
    // ---- and the 8 neighbor rows (k=1..4) for the column-distance search.
    const float* __restrict__ xb = x + (size_t)b * (C_ * HW) + h * W_ + tx;
    const float x0 = xb[0];
    const float x1 = xb[HW];
    const float x2 = xb[2 * HW];
    const float x3 = xb[3 * HW];
    const int yv = yb[h * W_ + tx];
    int nbu[4], nbd[4];                  // clamped addresses; masked below
#pragma unroll
    for (int k = 1; k <= 4; ++k) {
        nbu[k - 1] = yb[max(h - k, 0) * W_ + tx];
        nbd[k - 1] = yb[min(h + k, H_ - 1) * W_ + tx];
    }

    // ---- column distance^2: nearest row with a different label ----
    float g2 = INF2;
    bool done = false;
#pragma unroll
    for (int k = 1; k <= 4; ++k) {
        const bool hit = ((h - k >= 0) && nbu[k - 1] != yv) ||
                         ((h + k < H_) && nbd[k - 1] != yv);
        if (!done && hit) { g2 = (float)(k * k); done = true; }
    }
    if (__any(!done)) {                  // rare: unresolved past k=4
        for (int k = 5; k < H_; ++k) {
            const int hu = h - k, hd = h + k;
            const int u = yb[max(hu, 0) * W_ + tx];
            const int dn = yb[min(hd, H_ - 1) * W_ + tx];
            const bool hit = ((hu >= 0) && u != yv) || ((hd < H_) && dn != yv);
            if (!done && hit) { g2 = (float)(k * k); done = true; }
            if (__all(done)) break;
            if (hu < 0 && hd >= H_) break;
        }
    }

    __shared__ uint2 s2[W_];             // {g2 bits, label}
    s2[tx] = make_uint2(__float_as_uint(g2), (unsigned)yv);
    __syncthreads();

    // ---- exact min-plus along W, adaptive radius, clamped indices ----
    // cand(j,k) = (label[j]==yv ? g2col[j] : 0) + k^2 ; a clamped j is
    // dominated by its true-k evaluation, so clamping never changes the min.
    const unsigned cu = (unsigned)yv;
    float m = g2;                        // j = x candidate
#define CAND(J, K2) ({ int j_ = (J); j_ = min(max(j_, 0), W_ - 1);            \
                       const uint2 v_ = s2[j_];                               \
                       (((v_.y == cu) ? __uint_as_float(v_.x) : 0.0f) + (K2)); })
    m = fminf(m, fminf(CAND(tx - 1, 1.0f),  CAND(tx + 1, 1.0f)));
    m = fminf(m, fminf(CAND(tx - 2, 4.0f),  CAND(tx + 2, 4.0f)));
    m = fminf(m, fminf(CAND(tx - 3, 9.0f),  CAND(tx + 3, 9.0f)));
    m = fminf(m, fminf(CAND(tx - 4, 16.0f), CAND(tx + 4, 16.0f)));
    if (__any(m > 25.0f)) {
        float k2 = 25.0f, tk1 = 11.0f;   // k^2, 2k+1 (exact ints in f32)
        for (int k = 5; k < W_; ++k) {
            m = fminf(m, fminf(CAND(tx - k, k2), CAND(tx + k, k2)));
            k2 += tk1; tk1 += 2.0f;
            if (__all(k2 >= m)) break;   // next k can't improve any lane
        }
    }
#undef CAND
    const float d = sqrtf(m);            // own-class distance (>= 1)

    // ---- softmax over channels; contribution split ----
    const float xm = fmaxf(fmaxf(x0, x1), fmaxf(x2, x3));
    const float e0 = __expf(x0 - xm), e1 = __expf(x1 - xm);
    const float e2 = __expf(x2 - xm), e3 = __expf(x3 - xm);
    const float se = e0 + e1 + e2 + e3;
    const float inv = 1.0f / se;
    const float ec = (yv == 0) ? e0 : (yv == 1) ? e1 : (yv == 2) ? e2 : e3;
    const float p = ec * inv;            // own-class probability
    float T = (se - ec) * inv;           // other 3 classes: r = 1
    const float a = p * d;               // own class: needs /(mx+eps) later

    float A0 = (yv == 0) ? a : 0.0f, M0 = (yv == 0) ? d : 0.0f;
    float A1 = (yv == 1) ? a : 0.0f, M1 = (yv == 1) ? d : 0.0f;
    float A2 = (yv == 2) ? a : 0.0f, M2 = (yv == 2) ? d : 0.0f;
    float A3 = (yv == 3) ? a : 0.0f, M3 = (yv == 3) ? d : 0.0f;

    // ---- fixed-order wave butterfly + cross-wave combine ----
#pragma unroll
    for (int off = 1; off < 64; off <<= 1) {
        A0 += __shfl_xor(A0, off); A1 += __shfl_xor(A1, off);
        A2 += __shfl_xor(A2, off); A3 += __shfl_xor(A3, off);
        T  += __shfl_xor(T,  off);
        M0 = fmaxf(M0, __shfl_xor(M0, off)); M1 = fmaxf(M1, __shfl_xor(M1, off));
        M2 = fmaxf(M2, __shfl_xor(M2, off)); M3 = fmaxf(M3, __shfl_xor(M3, off));
    }
    __shared__ float red[4][9];
    const int wid = tx >> 6;
    if ((tx & 63) == 0) {
        red[wid][0] = A0; red[wid][1] = A1; red[wid][2] = A2; red[wid][3] = A3;
        red[wid][4] = M0; red[wid][5] = M1; red[wid][6] = M2; red[wid][7] = M3;
        red[wid][8] = T;
    }
    __syncthreads();
    if (tx < 9) {   // slots 0-3: A sums, 4-7: M maxes, 8: T sum
        const float v0 = red[0][tx], v1 = red[1][tx], v2 = red[2][tx], v3 = red[3][tx];
        const float r = (tx >= 4 && tx < 8) ? fmaxf(fmaxf(v0, v1), fmaxf(v2, v3))
                                            : (v0 + v1) + (v2 + v3);
        P[tx * NROW + row] = r;
    }
}

// Single block: P[slot][b*256+h] -> out = (T - sum_{b,c} A/(M+1e-15)) / (B*C*H*W)
__global__ void finish_kernel(const float* __restrict__ P, float* __restrict__ out) {
    const int t = threadIdx.x;           // 256 threads; 32 groups of 8 = (b,c)
    const int g = t >> 3, l = t & 7;
    const int b = g >> 2, c = g & 3;
    const float* Pa = P + c * NROW + b * H_;
    const float* Pm = P + (4 + c) * NROW + b * H_;
    float a = 0.0f, mm = 0.0f;
#pragma unroll 8
    for (int i = 0; i < 32; ++i) {
        a += Pa[l + (i << 3)];
        mm = fmaxf(mm, Pm[l + (i << 3)]);
    }
#pragma unroll
    for (int off = 1; off < 8; off <<= 1) {
        a += __shfl_xor(a, off);
        mm = fmaxf(mm, __shfl_xor(mm, off));
    }
    float tt = 0.0f;
    const float* Pt = P + 8 * NROW;
#pragma unroll
    for (int i = 0; i < 8; ++i) tt += Pt[t + (i << 8)];
#pragma unroll
    for (int off = 1; off < 64; off <<= 1) tt += __shfl_xor(tt, off);
    __shared__ float sV[32];
    __shared__ float sT[4];
    if (l == 0) sV[g] = a / (mm + 1e-15f);
    if ((t & 63) == 0) sT[t >> 6] = tt;
    __syncthreads();
    if (t == 0) {
        float S = 0.0f;
#pragma unroll
        for (int i = 0; i < 32; ++i) S += sV[i];
        const float T = (sT[0] + sT[1]) + (sT[2] + sT[3]);
        out[0] = (T - S) * (1.0f / 2097152.0f);   // / (B*C*H*W)
    }
}

extern "C" void kernel_launch(void* const* d_in, const int* in_sizes, int n_in,
                              void* d_out, int out_size, void* d_ws, size_t ws_size,
                              hipStream_t stream) {
    const float* x = (const float*)d_in[0];   // [B, C, H, W] f32
    const int* y = (const int*)d_in[1];       // [B, 1, H, W] i32
    float* out = (float*)d_out;               // scalar f32
    float* P = (float*)d_ws;                  // [9][NROW] partials (72 KB)

    fused_kernel<<<NROW, 256, 0, stream>>>(y, x, P);
    finish_kernel<<<1, 256, 0, stream>>>(P, out);
}